// Round 8
// baseline (526.905 us; speedup 1.0000x reference)
//
#include <hip/hip_runtime.h>
#include <math.h>

typedef _Float16 f16;
typedef _Float16 f16x2 __attribute__((ext_vector_type(2)));
typedef _Float16 f16x8 __attribute__((ext_vector_type(8)));
typedef float f32x16 __attribute__((ext_vector_type(16)));

#define BATCH 64
#define IC 18
#define OC 32
#define H 224
#define W 224
#define RSTRIP 28
#define NSTRIP 8              // 224/28
#define NTILE 7               // 224/32
#define WPB 4                 // waves per block
#define KPW (NTILE * NSTRIP)  // 56 wave-units per batch
#define UNITS (BATCH * KPW)   // 3584 wave-units
#define NBLOCK (UNITS / WPB)  // 896 blocks
#define NITER 30              // input rows r0-1 .. r0+28 (= 6 x 5, static unroll)
#define RECS 34               // records per slot (cols 32t-1 .. 32t+32)
#define RECW 24               // f16 per record (48 B): 0..17 ic, 18..19 patch, 20..23 pad
#define SLOTF (RECS * RECW)   // 816 f16 per slot
#define BSTRIDE 72            // B-matrix LDS pitch (144 B, conflict-free)
#define NUM_L2 9

#define MF(a_, b_, c_) c_ = __builtin_amdgcn_mfma_f32_32x32x16_f16((a_), (b_), (c_), 0, 0, 0)

// ---------------------------------------------------------------------------
// Conv3x3(18->32, SAME) + bias + ReLU + global-sum-pool, implicit-GEMM MFMA.
// 3584 independent WAVE-UNITS (b, 32-col tile, 28-row strip); no main-loop
// barriers, no atomics. ROW-STATIONARY: each input row is ds_read ONCE
// (4 x b128) and feeds 12 MFMAs in 3 INDEPENDENT chains (kh0/1/2 -> 3
// rotating accs) -- fixes round-7's serial 12-deep single-acc MFMA chain.
// Retire of a completed output row happens at the START of the next
// iteration (the freed acc is that iteration's kh0 target), overlapping
// retire-VALU with ds_read latency and giving the last MFMA a full
// iteration of slack. 2-slot LDS double buffer, slot = (gi+1)&1 (static
// via 6-unrolled loop; r0 is always even).
// K' = 64 packing (verified rounds 5/7): [kw0 ic0..17 | kw2 ic16,17 | pad4 |
// kw1 ic0..17 | pad6 | kw2 ic0..15]; record p main = x[col0+p][ic0..17],
// patch = x[col0+p+2][ic16,17], col0 = 32t-1; A[px] = 4 aligned b128 at
// f16 index 24*px (+16c) + 8*lh; stride-48B lane pattern = conflict-free.
// ---------------------------------------------------------------------------
__global__ __launch_bounds__(256, 3)
void conv_mfma_kernel(const float* __restrict__ x,
                      const float* __restrict__ conv_w,
                      const float* __restrict__ conv_b,
                      float* __restrict__ part) {
    __shared__ __align__(16) f16 slab[WPB][2][SLOTF];   // 13056 B
    __shared__ __align__(16) f16 Bw[3 * 32 * BSTRIDE];  // 13824 B

    const int tid = threadIdx.x;
    const int l   = tid & 63;
    const int wv  = tid >> 6;
    const int lm  = l & 31;          // A-row(px) / B&D col(oc)
    const int lh  = l >> 5;          // k-half

    const int unit = blockIdx.x * WPB + wv;
    const int b    = unit / KPW;
    const int rem  = unit - b * KPW;
    const int t    = rem % NTILE;
    const int s    = rem / NTILE;
    const int r0   = s * RSTRIP;     // always even
    const int col0 = t * 32 - 1;     // column of record 0

    // ---- weights -> Bw[kh][oc][k'] (all threads, one barrier) ----
    for (int idx = tid; idx < 3 * 32 * 64; idx += 256) {
        const int kh = idx >> 11;
        const int oc = (idx >> 6) & 31;
        const int kp = idx & 63;
        int kw = 0, ic = 0, valid = 1;
        if (kp < 18)      { kw = 0; ic = kp; }
        else if (kp < 20) { kw = 2; ic = 16 + (kp - 18); }
        else if (kp < 24) { valid = 0; }
        else if (kp < 42) { kw = 1; ic = kp - 24; }
        else if (kp < 48) { valid = 0; }
        else              { kw = 2; ic = kp - 48; }
        Bw[(kh * 32 + oc) * BSTRIDE + kp] =
            (f16)(valid ? conv_w[oc * 162 + ic * 9 + kh * 3 + kw] : 0.f);
    }

    // ---- per-wave: zero pad slots of both slots (read by A, masked by B=0;
    // must be finite -- NaN*0 = NaN would poison the accumulator) ----
    for (int i = l; i < 2 * RECS; i += 64) {
        const int sl  = (i >= RECS) ? 1 : 0;
        const int rec = sl ? (i - RECS) : i;
        f16* q = &slab[wv][sl][rec * RECW];
        f16x2 z2; z2[0] = (f16)0.f; z2[1] = (f16)0.f;
        *reinterpret_cast<f16x2*>(&q[20]) = z2;
        *reinterpret_cast<f16x2*>(&q[22]) = z2;
        if (rec >= 32) *reinterpret_cast<f16x2*>(&q[18]) = z2;  // recs 32,33 patch->0
    }
    __syncthreads();   // Bw ready

    // ---- staging roles: 2 lanes per record; h=0 -> ic0..7, h=1 -> ic8..17 ----
    const int p   = l >> 1;            // record 0..31
    const int hh  = l & 1;
    const int col = col0 + p;
    const bool colok = (col >= 0) & (col < W);
    const size_t plane = (size_t)H * W;
    const float* xb = x + ((size_t)b * IC + 8 * hh) * plane + col;
    // extras: lanes 0..3 also stage records 32,33 (cols 32t+31, 32t+32)
    const int er   = 32 + (l >> 1);    // valid for l<4
    const int ecol = col0 + er;
    const bool eok = (l < 4) & (ecol < W);
    const float* xe = x + ((size_t)b * IC + 8 * hh) * plane + ecol;

    auto STAGE_LOAD = [&](int g, float* sv, float* sve) {
        const bool rok = (g >= 0) & (g < H);
        if (rok & colok) {
            const float* q = xb + (size_t)g * W;
            #pragma unroll
            for (int j = 0; j < 8; ++j) sv[j] = q[j * plane];
            if (hh) { sv[8] = q[8 * plane]; sv[9] = q[9 * plane]; }
            else    { sv[8] = 0.f; sv[9] = 0.f; }
        } else {
            #pragma unroll
            for (int j = 0; j < 10; ++j) sv[j] = 0.f;
        }
        if (l < 4) {
            if (rok & eok) {
                const float* q = xe + (size_t)g * W;
                #pragma unroll
                for (int j = 0; j < 8; ++j) sve[j] = q[j * plane];
                if (hh) { sve[8] = q[8 * plane]; sve[9] = q[9 * plane]; }
                else    { sve[8] = 0.f; sve[9] = 0.f; }
            } else {
                #pragma unroll
                for (int j = 0; j < 10; ++j) sve[j] = 0.f;
            }
        }
    };
    auto STAGE_WRITE = [&](int slot, const float* sv, const float* sve) {
        f16* sw = &slab[wv][slot][0];
        f16x8 v;
        #pragma unroll
        for (int j = 0; j < 8; ++j) v[j] = (f16)sv[j];
        *reinterpret_cast<f16x8*>(&sw[p * RECW + 8 * hh]) = v;
        if (hh) {
            f16x2 c2; c2[0] = (f16)sv[8]; c2[1] = (f16)sv[9];   // ic16,17 of col
            *reinterpret_cast<f16x2*>(&sw[p * RECW + 16]) = c2;
            if (p >= 2)                                          // patch of rec p-2
                *reinterpret_cast<f16x2*>(&sw[(p - 2) * RECW + 18]) = c2;
        }
        if (l < 4) {
            f16x8 w8;
            #pragma unroll
            for (int j = 0; j < 8; ++j) w8[j] = (f16)sve[j];
            *reinterpret_cast<f16x8*>(&sw[er * RECW + 8 * hh]) = w8;
            if (hh) {
                f16x2 e2; e2[0] = (f16)sve[8]; e2[1] = (f16)sve[9];
                *reinterpret_cast<f16x2*>(&sw[er * RECW + 16]) = e2;
                *reinterpret_cast<f16x2*>(&sw[(er - 2) * RECW + 18]) = e2; // patches 30,31
            }
        }
    };

    // ---- prologue: stage input row r0-1 into slot 1 ((r0-1)&1 with r0 even) ----
    {
        float sv[10], sve[10];
        STAGE_LOAD(r0 - 1, sv, sve);
        STAGE_WRITE(1, sv, sve);
    }

    // ---- B fragments to registers (once) ----
    f16x8 bfr[3][4];
    #pragma unroll
    for (int kh = 0; kh < 3; ++kh)
        #pragma unroll
        for (int cc = 0; cc < 4; ++cc)
            bfr[kh][cc] = *reinterpret_cast<const f16x8*>(
                &Bw[(kh * 32 + lm) * BSTRIDE + 16 * cc + 8 * lh]);

    const float bias = conv_b[lm];
    float pacc = 0.f;
    f32x16 a0c, a1c, a2c;
    #pragma unroll
    for (int i = 0; i < 16; ++i) { a0c[i] = 0.f; a1c[i] = 0.f; a2c[i] = 0.f; }

    const int abase = RECW * lm + 8 * lh;   // f16 offset of A chunk 0 within a slot

    // ITER(gi): input row g = r0-1+gi, read slot RD = (gi+1)&1 (static).
    // kh0 -> out g+1 (aK0), kh1 -> out g (aK1), kh2 -> out g-1 (aK2).
    // aK0 (= prev iter's aK2) holds completed out-row g-2: retire it FIRST.
    auto ITER = [&](int gi, f32x16& aK0, f32x16& aK1, f32x16& aK2, int RD) {
        const int g = r0 - 1 + gi;
        const bool do_stage = (gi != NITER - 1);
        float sv[10], sve[10];
        if (do_stage) STAGE_LOAD(g + 1, sv, sve);    // issue loads early (T14)

        const f16* sb = &slab[wv][RD][0];
        const f16x8 a0 = *reinterpret_cast<const f16x8*>(&sb[abase]);
        const f16x8 a1 = *reinterpret_cast<const f16x8*>(&sb[abase + 16]);
        const f16x8 a2 = *reinterpret_cast<const f16x8*>(&sb[abase + 32]);
        const f16x8 a3 = *reinterpret_cast<const f16x8*>(&sb[abase + 48]);

        // retire out-row g-2 from aK0 (VALU overlaps the ds_read latency)
        if (gi >= 3) {
            float ssum = 0.f;
            #pragma unroll
            for (int i = 0; i < 16; ++i) ssum += fmaxf(aK0[i] + bias, 0.f);
            pacc += ssum;
        }
        #pragma unroll
        for (int i = 0; i < 16; ++i) aK0[i] = 0.f;

        // 12 MFMAs, 3 independent chains interleaved (kh0/kh1/kh2)
        MF(a0, bfr[0][0], aK0); MF(a0, bfr[1][0], aK1); MF(a0, bfr[2][0], aK2);
        MF(a1, bfr[0][1], aK0); MF(a1, bfr[1][1], aK1); MF(a1, bfr[2][1], aK2);
        MF(a2, bfr[0][2], aK0); MF(a2, bfr[1][2], aK1); MF(a2, bfr[2][2], aK2);
        MF(a3, bfr[0][3], aK0); MF(a3, bfr[1][3], aK1); MF(a3, bfr[2][3], aK2);

        if (do_stage) STAGE_WRITE(RD ^ 1, sv, sve);  // write late (after vmcnt)
    };

    // 30 iterations, 6-unrolled: acc rotation period 3 x slot parity period 2
    for (int g6 = 0; g6 < NITER; g6 += 6) {
        ITER(g6 + 0, a2c, a1c, a0c, 1);
        ITER(g6 + 1, a0c, a2c, a1c, 0);
        ITER(g6 + 2, a1c, a0c, a2c, 1);
        ITER(g6 + 3, a2c, a1c, a0c, 0);
        ITER(g6 + 4, a0c, a2c, a1c, 1);
        ITER(g6 + 5, a1c, a0c, a2c, 0);
    }
    // final out-row r0+27 sits in the last iteration's aK2 = a2c
    {
        float ssum = 0.f;
        #pragma unroll
        for (int i = 0; i < 16; ++i) ssum += fmaxf(a2c[i] + bias, 0.f);
        pacc += ssum;
    }

    // lanes l and l^32 hold the two px-halves of the same oc
    pacc += __shfl_xor(pacc, 32);
    if (l < 32) part[((size_t)b * KPW + rem) * 32 + lm] = pacc;  // no atomic
}

// ---------------------------------------------------------------------------
// Head: one block per batch row. feat = [sum(part)/50176, pred];
// f = relu(feat @ fc1_w^T + b1); logits = f @ fc2_w^T + b2;
// hierarchical mask from argmax(pred); softmax.
// ---------------------------------------------------------------------------
__global__ void head_kernel(const float* __restrict__ part,
                            const float* __restrict__ pred,
                            const float* __restrict__ fc1_w,
                            const float* __restrict__ fc1_b,
                            const float* __restrict__ fc2_w,
                            const float* __restrict__ fc2_b,
                            float* __restrict__ out) {
    __shared__ float feat[34];
    __shared__ float fsh[64];
    __shared__ float lsh[NUM_L2];
    const int b = blockIdx.x;
    const int tI = threadIdx.x;

    if (tI < 32) {
        float sres = 0.f;
        const float* pp = part + (size_t)b * KPW * 32 + tI;
        for (int k = 0; k < KPW; ++k) sres += pp[k * 32];
        feat[tI] = sres * (1.f / (float)(H * W));
    } else if (tI < 34) {
        feat[tI] = pred[b * 2 + (tI - 32)];
    }
    __syncthreads();

    {
        float sum = fc1_b[tI];
        #pragma unroll
        for (int k = 0; k < 34; ++k) sum += feat[k] * fc1_w[tI * 34 + k];
        fsh[tI] = fmaxf(sum, 0.f);
    }
    __syncthreads();

    if (tI < NUM_L2) {
        float sum = fc2_b[tI];
        #pragma unroll
        for (int j = 0; j < 64; ++j) sum += fsh[j] * fc2_w[tI * 64 + j];
        lsh[tI] = sum;
    }
    __syncthreads();

    if (tI == 0) {
        const int idx = (pred[b * 2 + 1] > pred[b * 2 + 0]) ? 1 : 0;  // first-max ties
        const int lo = idx ? 4 : 0;
        const int hi = idx ? 9 : 4;
        float m = -1e30f;
        for (int c = lo; c < hi; ++c) m = fmaxf(m, lsh[c]);
        float e[NUM_L2];
        float ssum = 0.f;
        for (int c = 0; c < NUM_L2; ++c) {
            const float v = (c >= lo && c < hi) ? expf(lsh[c] - m) : 0.f;
            e[c] = v;
            ssum += v;
        }
        const float rs = 1.f / ssum;
        for (int c = 0; c < NUM_L2; ++c) out[b * NUM_L2 + c] = e[c] * rs;
    }
}

extern "C" void kernel_launch(void* const* d_in, const int* in_sizes, int n_in,
                              void* d_out, int out_size, void* d_ws, size_t ws_size,
                              hipStream_t stream) {
    const float* x      = (const float*)d_in[0];
    const float* pred   = (const float*)d_in[1];
    const float* conv_w = (const float*)d_in[2];
    const float* conv_b = (const float*)d_in[3];
    const float* fc1_w  = (const float*)d_in[4];
    const float* fc1_b  = (const float*)d_in[5];
    const float* fc2_w  = (const float*)d_in[6];
    const float* fc2_b  = (const float*)d_in[7];
    float* out  = (float*)d_out;
    float* part = (float*)d_ws;   // [64][56][32] per-wave pool partials (fully overwritten)

    conv_mfma_kernel<<<NBLOCK, 256, 0, stream>>>(x, conv_w, conv_b, part);
    head_kernel<<<BATCH, 64, 0, stream>>>(part, pred, fc1_w, fc1_b, fc2_w, fc2_b, out);
}